// Round 7
// baseline (111.576 us; speedup 1.0000x reference)
//
#include <hip/hip_runtime.h>
#include <hip/hip_bf16.h>

#define S_ 8192
#define H_ 8
#define D_ 64
#define M_ 64
#define BH_ 32
#define CPK_ 80          // buf1/partial row stride (c 0..79, den at c=64)
#define NCHQ 16
#define TILE 64
#define QTILES (S_ / NCHQ / TILE)   // 8

typedef short bf16x8 __attribute__((ext_vector_type(8)));
typedef float f32x4 __attribute__((ext_vector_type(4)));

constexpr float XS_ = 0.35355339059327373f * 1.4426950408889634f; // D^-1/4 * log2(e)
constexpr float HS_ = 0.34657359027997264f;                        // ln2/2
constexpr float EPS_ = 1e-6f;

__device__ __forceinline__ unsigned short f2bf(float f) {
    unsigned int u = __float_as_uint(f);
    u += 0x7FFFu + ((u >> 16) & 1u);          // RNE
    return (unsigned short)(u >> 16);
}
// paired RNE conversion -> v_cvt_pk_bf16_f32 (lo in low 16 bits)
__device__ __forceinline__ unsigned int pkbf(float lo, float hi) {
    __hip_bfloat162 t = __float22bfloat162_rn(float2{lo, hi});
    return *reinterpret_cast<unsigned int*>(&t);
}
__device__ __forceinline__ float fexp2(float x) { return __builtin_amdgcn_exp2f(x); }

#define MFMA(a, b, c) __builtin_amdgcn_mfma_f32_16x16x32_bf16((a), (b), (c), 0, 0, 0)
#define SWZ(byteoff, row) ((byteoff) ^ (((row) & 7) << 4))

// ---------------------------------------------------------------------------
// Phase K — DENSE global reads. Block = 512 thr / 8 waves, covers (s-chunk, b)
// for ALL 8 heads: staging loads are fully coalesced (1KB/instr over
// contiguous [s][h][d]).  Per 16-row tile: stage k (bf16, scaled, row-major
// + XOR swizzle) and v (sigma-slot transpose layout, as r6) into LDS; per-row
// h' computed at stage time from f32 into hL.  Wave w consumes head w:
// P = mfma(K, projT); E stays in registers in sigma A-layout (r6 trick);
// EV-MFMA every 2 tiles (K=32).  No cross-wave reduce: wave w owns the
// full 64x80 partial for bh = 8b + w.
// ---------------------------------------------------------------------------
__global__ void __launch_bounds__(512, 2)
fa_k(const float* __restrict__ ks, const float* __restrict__ vs,
     const float* __restrict__ proj, float* __restrict__ partial,
     int sch, int tiles)
{
    const int chunk = blockIdx.x;
    const int b     = blockIdx.y;
    const int tid = threadIdx.x, w8 = tid >> 6, lane = tid & 63;
    const int l15 = lane & 15, g = lane >> 4;

    __shared__ __align__(16) char kT[16 * 8 * 128];   // [s][h][d] bf16, 16KB
    __shared__ __align__(16) char vT[8 * 64 * 64];    // [h][c][slot] bf16, 32KB
    __shared__ float hL[16 * 8];                      // h' per (s,h)

    const int s0 = chunk * tiles * 16;
    const float4* kf4 = (const float4*)(ks + ((size_t)b * S_ + s0) * (H_ * D_));
    const float4* vf4 = (const float4*)(vs + ((size_t)b * S_ + s0) * (H_ * D_));

    // proj B-fragments: B[k=d][n=m]: lane: m = mt*16+l15, d = g*8+j (+32*kk)
    bf16x8 pf[4][2];
#pragma unroll
    for (int mt = 0; mt < 4; ++mt)
#pragma unroll
        for (int kk = 0; kk < 2; ++kk) {
            const float* p = proj + (mt * 16 + l15) * D_ + kk * 32 + g * 8;
            float4 a = *(const float4*)p, c = *(const float4*)(p + 4);
            union { bf16x8 v; unsigned int u[4]; } F;
            F.u[0] = pkbf(a.x, a.y); F.u[1] = pkbf(a.z, a.w);
            F.u[2] = pkbf(c.x, c.y); F.u[3] = pkbf(c.z, c.w);
            pf[mt][kk] = F.v;
        }

    // ones-column B-frag: B[k][c]=1 iff c==64 (lane l15==0); sigma-invariant
    bf16x8 onef = {0, 0, 0, 0, 0, 0, 0, 0};
    if (l15 == 0) {
#pragma unroll
        for (int j = 0; j < 8; ++j) onef[j] = (short)0x3F80;
    }

    f32x4 acc[4][5];
#pragma unroll
    for (int mt = 0; mt < 4; ++mt)
#pragma unroll
        for (int ci = 0; ci < 5; ++ci) acc[mt][ci] = (f32x4){0.f, 0.f, 0.f, 0.f};

    f32x4 paE[4];
    float hrE[4];

    // dense tile load: instr j reads 1KB contiguous per wave
    auto loadT = [&](int t, float4* kp, float4* vp) {
        size_t base = (size_t)t * 2048 + w8 * 256 + lane;
#pragma unroll
        for (int j = 0; j < 4; ++j) {
            kp[j] = kf4[base + j * 64];
            vp[j] = vf4[base + j * 64];
        }
    };

    // lane l, instr j holds float4 at pos l15 of vrow = w8*16 + j*4 + g
    auto stage = [&](const float4* kp, const float4* vp, int tpar) {
#pragma unroll
        for (int j = 0; j < 4; ++j) {
            int vrow = w8 * 16 + j * 4 + g;
            int sl = vrow >> 3, h = vrow & 7;
            float4 kx = kp[j];
            kx.x *= XS_; kx.y *= XS_; kx.z *= XS_; kx.w *= XS_;
            float sq = kx.x*kx.x + kx.y*kx.y + kx.z*kx.z + kx.w*kx.w;
            sq += __shfl_xor(sq, 1); sq += __shfl_xor(sq, 2);
            sq += __shfl_xor(sq, 4); sq += __shfl_xor(sq, 8);
            if (l15 == 0) hL[sl * 8 + h] = sq * HS_ + 3.0f;

            unsigned long long kpk = (unsigned long long)pkbf(kx.x, kx.y)
                                   | ((unsigned long long)pkbf(kx.z, kx.w) << 32);
            int kb2 = (sl * 1024 + h * 128 + l15 * 8) ^ (((sl + h) & 7) << 4);
            *(unsigned long long*)(kT + kb2) = kpk;

            unsigned int v01 = pkbf(vp[j].x, vp[j].y);
            unsigned int v23 = pkbf(vp[j].z, vp[j].w);
            int row32 = tpar * 16 + sl;
            int slot2 = 2 * (((row32 >> 2) & 3) * 8 + 4 * (row32 >> 4) + (row32 & 3));
            char* vbase = vT + h * 4096 + l15 * 256;     // c0 = l15*4
            *(unsigned short*)(vbase +   0 + (slot2 ^  0)) = (unsigned short)v01;
            *(unsigned short*)(vbase +  64 + (slot2 ^ 16)) = (unsigned short)(v01 >> 16);
            *(unsigned short*)(vbase + 128 + (slot2 ^ 32)) = (unsigned short)v23;
            *(unsigned short*)(vbase + 192 + (slot2 ^ 48)) = (unsigned short)(v23 >> 16);
        }
    };

    auto consume = [&](int t) {
        float hrow = hL[l15 * 8 + w8];
        int key = ((l15 + w8) & 7) << 4;
        int kb2 = l15 * 1024 + w8 * 128 + g * 16;
        bf16x8 kA0 = *(const bf16x8*)(kT + (kb2 ^ key));
        bf16x8 kA1 = *(const bf16x8*)(kT + ((kb2 + 64) ^ key));
        f32x4 pa[4];
#pragma unroll
        for (int mt = 0; mt < 4; ++mt) {
            pa[mt] = (f32x4){0.f, 0.f, 0.f, 0.f};
            pa[mt] = MFMA(kA0, pf[mt][0], pa[mt]);
            pa[mt] = MFMA(kA1, pf[mt][1], pa[mt]);
        }
        float hr[4];
#pragma unroll
        for (int r = 0; r < 4; ++r) hr[r] = __shfl(hrow, 4 * g + r);

        if ((t & 1) == 0) {
#pragma unroll
            for (int mt = 0; mt < 4; ++mt) paE[mt] = pa[mt];
#pragma unroll
            for (int r = 0; r < 4; ++r) hrE[r] = hr[r];
        } else {
            bf16x8 eA[4];
#pragma unroll
            for (int mt = 0; mt < 4; ++mt) {
                union { bf16x8 v; unsigned int u[4]; } E;
                E.u[0] = pkbf(fexp2(paE[mt][0]-hrE[0]), fexp2(paE[mt][1]-hrE[1]));
                E.u[1] = pkbf(fexp2(paE[mt][2]-hrE[2]), fexp2(paE[mt][3]-hrE[3]));
                E.u[2] = pkbf(fexp2(pa[mt][0]-hr[0]),   fexp2(pa[mt][1]-hr[1]));
                E.u[3] = pkbf(fexp2(pa[mt][2]-hr[2]),   fexp2(pa[mt][3]-hr[3]));
                eA[mt] = E.v;
            }
            const char* vb2 = vT + w8 * 4096;
            bf16x8 vB[4];
#pragma unroll
            for (int ct = 0; ct < 4; ++ct) {
                int c = ct * 16 + l15;
                vB[ct] = *(const bf16x8*)(vb2 + c * 64 + ((16 * g) ^ ((c & 3) << 4)));
            }
#pragma unroll
            for (int mt = 0; mt < 4; ++mt) {
#pragma unroll
                for (int ct = 0; ct < 4; ++ct)
                    acc[mt][ct] = MFMA(eA[mt], vB[ct], acc[mt][ct]);
                acc[mt][4] = MFMA(eA[mt], onef, acc[mt][4]);
            }
        }
    };

    float4 kA_[4], vA_[4], kB_[4], vB_[4];
    loadT(0, kA_, vA_);
    for (int t = 0; t < tiles; t += 2) {
        __syncthreads();
        stage(kA_, vA_, 0);
        if (t + 1 < tiles) loadT(t + 1, kB_, vB_);
        __syncthreads();
        consume(t);
        __syncthreads();
        stage(kB_, vB_, 1);
        if (t + 2 < tiles) loadT(t + 2, kA_, vA_);
        __syncthreads();
        consume(t + 1);
    }

    // wave w owns the full partial for bh = 8b + w
    float* dst = partial + ((size_t)(b * 8 + w8) * sch + chunk) * (M_ * CPK_);
#pragma unroll
    for (int mt = 0; mt < 4; ++mt)
#pragma unroll
        for (int ct = 0; ct < 5; ++ct)
#pragma unroll
            for (int r = 0; r < 4; ++r)
                dst[(mt * 16 + 4 * g + r) * CPK_ + ct * 16 + l15] = acc[mt][ct][r];
}

// ---------------------------------------------------------------------------
// Reduce partials over chunks -> buf1[bh][m][CPK_]
// ---------------------------------------------------------------------------
__global__ void __launch_bounds__(256)
fa_r(const float* __restrict__ partial, float* __restrict__ buf1, int nch)
{
    int e = blockIdx.x * 256 + threadIdx.x;
    if (e >= BH_ * M_ * CPK_) return;
    int bh = e / (M_ * CPK_);
    int r  = e - bh * (M_ * CPK_);
    const float* src = partial + (size_t)bh * nch * (M_ * CPK_) + r;
    float s0 = 0.f, s1 = 0.f, s2 = 0.f, s3 = 0.f;
    int ch = 0;
    for (; ch + 4 <= nch; ch += 4) {
        s0 += src[(size_t)(ch + 0) * (M_ * CPK_)];
        s1 += src[(size_t)(ch + 1) * (M_ * CPK_)];
        s2 += src[(size_t)(ch + 2) * (M_ * CPK_)];
        s3 += src[(size_t)(ch + 3) * (M_ * CPK_)];
    }
    for (; ch < nch; ++ch) s0 += src[(size_t)ch * (M_ * CPK_)];
    buf1[e] = (s0 + s1) + (s2 + s3);
}

// ---------------------------------------------------------------------------
// Phase Q: P = mfma(Qscaled, projT); e = exp2(P - h);
// Out^T-tiles: D[c][qrow] = mfma(buf1T, E_T); den = row c=64; out = num/den.
// ---------------------------------------------------------------------------
__global__ void __launch_bounds__(256)
fa_q(const float* __restrict__ qs, const float* __restrict__ proj,
     const float* __restrict__ buf1, float* __restrict__ out)
{
    const int chunk = blockIdx.x;
    const int bh    = blockIdx.y;
    const int b = bh >> 3, h = bh & 7;
    const int tid = threadIdx.x, wid = tid >> 6, lane = tid & 63;
    const int l15 = lane & 15, g = lane >> 4;

    __shared__ __align__(16) char eLb[2][TILE * M_ * 2];   // [qrow][m] bf16, swz by qrow
    __shared__ __align__(16) char b1tb[CPK_ * M_ * 2];     // [c][m] bf16, swz by c

    const int rows = S_ / NCHQ;
    const int s0 = chunk * rows;
    const size_t rs = (size_t)H_ * D_;
    const float* qb = qs + ((size_t)b * S_ * H_ + h) * D_;

    // stage buf1^T into LDS (c rows 65..79 are zeros in buf1 already)
    const float* b1 = buf1 + (size_t)bh * (M_ * CPK_);
    for (int i = tid; i < M_ * CPK_; i += 256) {
        int m = i / CPK_, c = i - m * CPK_;
        *(unsigned short*)(b1tb + SWZ(c * 128 + 2 * m, c)) = f2bf(b1[i]);
    }

    bf16x8 pf[4][2];
#pragma unroll
    for (int mt = 0; mt < 4; ++mt)
#pragma unroll
        for (int kk = 0; kk < 2; ++kk) {
            const float* p = proj + (mt * 16 + l15) * D_ + kk * 32 + g * 8;
            float4 a = *(const float4*)p, c = *(const float4*)(p + 4);
            union { bf16x8 v; unsigned int u[4]; } F;
            F.u[0] = pkbf(a.x, a.y); F.u[1] = pkbf(a.z, a.w);
            F.u[2] = pkbf(c.x, c.y); F.u[3] = pkbf(c.z, c.w);
            pf[mt][kk] = F.v;
        }
    __syncthreads();

    // buf1^T A-fragments, read once: A[c][m]: c = ci*16+l15, m = g*8+j (+32*kk)
    bf16x8 af3[5][2];
#pragma unroll
    for (int ci = 0; ci < 5; ++ci)
#pragma unroll
        for (int kk = 0; kk < 2; ++kk) {
            int c = ci * 16 + l15;
            af3[ci][kk] = *(const bf16x8*)(b1tb + SWZ(c * 128 + 16 * g + 64 * kk, c));
        }

    auto loadQ = [&](int t, float4* qp) {
        int sb = s0 + t * TILE;
        const float* qrow = qb + (size_t)(sb + wid * 16 + l15) * rs;
        qp[0] = *(const float4*)(qrow + g * 8);
        qp[1] = *(const float4*)(qrow + g * 8 + 4);
        qp[2] = *(const float4*)(qrow + 32 + g * 8);
        qp[3] = *(const float4*)(qrow + 32 + g * 8 + 4);
    };

    auto body = [&](int t, int p, const float4* qc, float4* qn) {
        if (t + 1 < QTILES) loadQ(t + 1, qn);

        float kx[16];
#pragma unroll
        for (int i = 0; i < 4; ++i) {
            kx[4 * i + 0] = qc[i].x * XS_; kx[4 * i + 1] = qc[i].y * XS_;
            kx[4 * i + 2] = qc[i].z * XS_; kx[4 * i + 3] = qc[i].w * XS_;
        }
        float sq = 0.f;
#pragma unroll
        for (int j = 0; j < 16; ++j) sq += kx[j] * kx[j];
        sq += __shfl_xor(sq, 16);
        sq += __shfl_xor(sq, 32);
        float hrow = sq * HS_ + 3.0f;

        union { bf16x8 v; unsigned int u[4]; } A0, A1;
#pragma unroll
        for (int i = 0; i < 4; ++i) {
            A0.u[i] = pkbf(kx[2 * i], kx[2 * i + 1]);
            A1.u[i] = pkbf(kx[8 + 2 * i], kx[9 + 2 * i]);
        }

        f32x4 pa[4];
#pragma unroll
        for (int mt = 0; mt < 4; ++mt) {
            pa[mt] = (f32x4){0.f, 0.f, 0.f, 0.f};
            pa[mt] = MFMA(A0.v, pf[mt][0], pa[mt]);
            pa[mt] = MFMA(A1.v, pf[mt][1], pa[mt]);
        }

        float hr[4];
#pragma unroll
        for (int r = 0; r < 4; ++r) hr[r] = __shfl(hrow, 4 * g + r);

        char* elp = eLb[p];
#pragma unroll
        for (int mt = 0; mt < 4; ++mt) {
            int m = mt * 16 + l15;
            float e0 = fexp2(pa[mt][0] - hr[0]);
            float e1 = fexp2(pa[mt][1] - hr[1]);
            float e2 = fexp2(pa[mt][2] - hr[2]);
            float e3 = fexp2(pa[mt][3] - hr[3]);
            unsigned int p01 = pkbf(e0, e1), p23 = pkbf(e2, e3);
            int q0 = wid * 16 + 4 * g;
            *(unsigned short*)(elp + SWZ((q0 + 0) * 128 + 2 * m, q0 + 0)) =
                (unsigned short)p01;
            *(unsigned short*)(elp + SWZ((q0 + 1) * 128 + 2 * m, q0 + 1)) =
                (unsigned short)(p01 >> 16);
            *(unsigned short*)(elp + SWZ((q0 + 2) * 128 + 2 * m, q0 + 2)) =
                (unsigned short)p23;
            *(unsigned short*)(elp + SWZ((q0 + 3) * 128 + 2 * m, q0 + 3)) =
                (unsigned short)(p23 >> 16);
        }
        __syncthreads();

        bf16x8 b3[2];
        {
            int qrow = wid * 16 + l15;
            b3[0] = *(const bf16x8*)(elp + SWZ(qrow * 128 + 16 * g, qrow));
            b3[1] = *(const bf16x8*)(elp + SWZ(qrow * 128 + 16 * g + 64, qrow));
        }
        f32x4 dt[5];
#pragma unroll
        for (int ci = 0; ci < 5; ++ci) {
            dt[ci] = (f32x4){0.f, 0.f, 0.f, 0.f};
            dt[ci] = MFMA(af3[ci][0], b3[0], dt[ci]);
            dt[ci] = MFMA(af3[ci][1], b3[1], dt[ci]);
        }

        float den = __shfl(dt[4][0], l15);      // lanes g==0 hold den[qrow=l15]
        float rd = 1.0f / fmaxf(den, EPS_);

        int sg = s0 + t * TILE + wid * 16 + l15;
        size_t base = (((size_t)b * S_ + sg) * H_ + h) * D_;
#pragma unroll
        for (int ci = 0; ci < 4; ++ci) {
            f32x4 o;
#pragma unroll
            for (int r = 0; r < 4; ++r) o[r] = dt[ci][r] * rd;
            *(f32x4*)(out + base + ci * 16 + 4 * g) = o;
        }
    };

    float4 qa[4], qb2[4];
    loadQ(0, qa);
    for (int t = 0; t < QTILES; t += 2) {
        body(t, 0, qa, qb2);
        body(t + 1, 1, qb2, qa);
    }
}

extern "C" void kernel_launch(void* const* d_in, const int* in_sizes, int n_in,
                              void* d_out, int out_size, void* d_ws, size_t ws_size,
                              hipStream_t stream)
{
    const float* qs   = (const float*)d_in[0];
    const float* ks   = (const float*)d_in[1];
    const float* vs   = (const float*)d_in[2];
    const float* proj = (const float*)d_in[3];
    float* out = (float*)d_out;

    size_t per = (size_t)(M_ * CPK_) * sizeof(float);
    int sch = 64;
    if ((size_t)BH_ * (size_t)(sch + 1) * per > ws_size) sch = 32;
    int tiles = S_ / sch / 16;                    // 8 (or 16)

    float* partial = (float*)d_ws;                // BH*sch*M*CPK
    float* buf1 = partial + (size_t)BH_ * sch * (M_ * CPK_);

    fa_k<<<dim3(sch, 4), 512, 0, stream>>>(ks, vs, proj, partial, sch, tiles);
    int nred = (BH_ * M_ * CPK_ + 255) / 256;
    fa_r<<<dim3(nred), 256, 0, stream>>>(partial, buf1, sch);
    fa_q<<<dim3(NCHQ, BH_), 256, 0, stream>>>(qs, proj, buf1, out);
}

// Round 8
// 74.153 us; speedup vs baseline: 1.5047x; 1.5047x over previous
//
#include <hip/hip_runtime.h>
#include <hip/hip_bf16.h>

#define S_ 8192
#define H_ 8
#define D_ 64
#define M_ 64
#define BH_ 32
#define CPK_ 80          // buf1/partial row stride (c 0..79, den at c=64)
#define NCH_ 16          // phase-K chunks
#define NCHQ 16
#define TILE 64
#define QTILES (S_ / NCHQ / TILE)   // 8

typedef short bf16x8 __attribute__((ext_vector_type(8)));
typedef float f32x4 __attribute__((ext_vector_type(4)));

constexpr float XS_ = 0.35355339059327373f * 1.4426950408889634f; // D^-1/4 * log2(e)
constexpr float HS_ = 0.34657359027997264f;                        // ln2/2
constexpr float EPS_ = 1e-6f;

__device__ __forceinline__ unsigned short f2bf(float f) {
    unsigned int u = __float_as_uint(f);
    u += 0x7FFFu + ((u >> 16) & 1u);          // RNE
    return (unsigned short)(u >> 16);
}
// paired RNE conversion -> v_cvt_pk_bf16_f32 (lo in low 16 bits)
__device__ __forceinline__ unsigned int pkbf(float lo, float hi) {
    __hip_bfloat162 t = __float22bfloat162_rn(float2{lo, hi});
    return *reinterpret_cast<unsigned int*>(&t);
}
__device__ __forceinline__ float fexp2(float x) { return __builtin_amdgcn_exp2f(x); }

#define MFMA(a, b, c) __builtin_amdgcn_mfma_f32_16x16x32_bf16((a), (b), (c), 0, 0, 0)
#define SWZ(byteoff, row) ((byteoff) ^ (((row) & 7) << 4))

// ---------------------------------------------------------------------------
// Phase K — r6's barrier-free wave-independent body + DEEP PREFETCH (MLP fix).
// 16-row iterations, 3-slot register rotation, 2 tiles in flight during
// compute (16 KB/wave outstanding vs r6's ~2 KB -> Little's-law coverage).
// P = mfma(Kscaled, projT); E stays in registers in sigma A-layout; V rows
// sigma-scattered to wave-private LDS; EV-MFMA every 2 iterations (K=32).
// Per-wave 64x80 partial, cross-wave reduce once at kernel end.
// ---------------------------------------------------------------------------
__global__ void __launch_bounds__(256, 2)
fa_k(const float* __restrict__ ks, const float* __restrict__ vs,
     const float* __restrict__ proj, float* __restrict__ partial)
{
    const int chunk = blockIdx.x;
    const int bh    = blockIdx.y;
    const int b = bh >> 3, h = bh & 7;
    const int tid = threadIdx.x, wid = tid >> 6, lane = tid & 63;
    const int l15 = lane & 15, g = lane >> 4;

    __shared__ __align__(16) char vT[4][2][64 * 64];  // [wave][window][c][slot2]
    __shared__ float red[M_ * CPK_];

    const size_t rs = (size_t)H_ * D_;
    const float* kb = ks + ((size_t)b * S_ * H_ + h) * D_;
    const float* vb = vs + ((size_t)b * S_ * H_ + h) * D_;
    const int rbase = chunk * 512 + wid * 128;        // wave-contiguous 128 rows

    // proj B-fragments: B[k=d][n=m]: lane: m = mt*16+l15, d = g*8+j (+32*kk)
    bf16x8 pf[4][2];
#pragma unroll
    for (int mt = 0; mt < 4; ++mt)
#pragma unroll
        for (int kk = 0; kk < 2; ++kk) {
            const float* p = proj + (mt * 16 + l15) * D_ + kk * 32 + g * 8;
            float4 a = *(const float4*)p, c = *(const float4*)(p + 4);
            union { bf16x8 v; unsigned int u[4]; } F;
            F.u[0] = pkbf(a.x, a.y); F.u[1] = pkbf(a.z, a.w);
            F.u[2] = pkbf(c.x, c.y); F.u[3] = pkbf(c.z, c.w);
            pf[mt][kk] = F.v;
        }

    // ones-column B-frag: B[k][c]=1 iff c==64 (lane l15==0); sigma-invariant
    bf16x8 onef = {0, 0, 0, 0, 0, 0, 0, 0};
    if (l15 == 0) {
#pragma unroll
        for (int j = 0; j < 8; ++j) onef[j] = (short)0x3F80;
    }

    f32x4 acc[4][5];
#pragma unroll
    for (int mt = 0; mt < 4; ++mt)
#pragma unroll
        for (int ci = 0; ci < 5; ++ci) acc[mt][ci] = (f32x4){0.f, 0.f, 0.f, 0.f};

    f32x4 paE[4];      // even-iter P carried to the odd iter
    float hrE[4];

    // one 16-row tile: 4 k float4 + 4 v float4 (row l15, cols g*8.. / 32+g*8..)
    auto loadX = [&](int t, float4* kp, float4* vp) {
        const float* kr = kb + (size_t)(rbase + t * 16 + l15) * rs;
        kp[0] = *(const float4*)(kr + g * 8);
        kp[1] = *(const float4*)(kr + g * 8 + 4);
        kp[2] = *(const float4*)(kr + 32 + g * 8);
        kp[3] = *(const float4*)(kr + 32 + g * 8 + 4);
        const float* vr = vb + (size_t)(rbase + t * 16 + l15) * rs;
        vp[0] = *(const float4*)(vr + g * 8);
        vp[1] = *(const float4*)(vr + g * 8 + 4);
        vp[2] = *(const float4*)(vr + 32 + g * 8);
        vp[3] = *(const float4*)(vr + 32 + g * 8 + 4);
    };

    auto body = [&](int t, const float4* kc, const float4* vc,
                    float4* kn2, float4* vn2) {
        if (t + 2 < 8) loadX(t + 2, kn2, vn2);    // keep 2 tiles in flight

        // scale + full-row h (row = l15; d-coverage across 4 g-lanes)
        float kx[16];
#pragma unroll
        for (int i = 0; i < 4; ++i) {
            kx[4*i+0] = kc[i].x * XS_; kx[4*i+1] = kc[i].y * XS_;
            kx[4*i+2] = kc[i].z * XS_; kx[4*i+3] = kc[i].w * XS_;
        }
        float sq = 0.f;
#pragma unroll
        for (int j = 0; j < 16; ++j) sq += kx[j] * kx[j];
        sq += __shfl_xor(sq, 16);
        sq += __shfl_xor(sq, 32);
        float hrow = sq * HS_ + 3.0f;

        union { bf16x8 v; unsigned int u[4]; } A0, A1;
#pragma unroll
        for (int i = 0; i < 4; ++i) {
            A0.u[i] = pkbf(kx[2*i], kx[2*i+1]);
            A1.u[i] = pkbf(kx[8+2*i], kx[9+2*i]);
        }

        f32x4 pa[4];
#pragma unroll
        for (int mt = 0; mt < 4; ++mt) {
            pa[mt] = (f32x4){0.f, 0.f, 0.f, 0.f};
            pa[mt] = MFMA(A0.v, pf[mt][0], pa[mt]);
            pa[mt] = MFMA(A1.v, pf[mt][1], pa[mt]);
        }

        float hr[4];
#pragma unroll
        for (int r = 0; r < 4; ++r) hr[r] = __shfl(hrow, 4 * g + r);

        // sigma-scatter v rows into this window's LDS buffer
        {
            char* vtp = (char*)vT + wid * 8192 + ((t >> 1) & 1) * 4096;
            int slot2 = 2 * (((l15 >> 2) & 3) * 8 + 4 * (t & 1) + (l15 & 3));
            float vv[16];
#pragma unroll
            for (int i = 0; i < 4; ++i) {
                vv[4*i+0] = vc[i].x; vv[4*i+1] = vc[i].y;
                vv[4*i+2] = vc[i].z; vv[4*i+3] = vc[i].w;
            }
#pragma unroll
            for (int p2 = 0; p2 < 4; ++p2) {
                int cA = g * 8 + 2 * p2;
                unsigned int pA = pkbf(vv[2*p2], vv[2*p2+1]);
                *(unsigned short*)(vtp + cA * 64 + (slot2 ^ ((cA & 3) << 4))) =
                    (unsigned short)pA;
                int cB = cA + 1;
                *(unsigned short*)(vtp + cB * 64 + (slot2 ^ ((cB & 3) << 4))) =
                    (unsigned short)(pA >> 16);
                int cC = 32 + cA;
                unsigned int pB = pkbf(vv[8+2*p2], vv[9+2*p2]);
                *(unsigned short*)(vtp + cC * 64 + (slot2 ^ ((cC & 3) << 4))) =
                    (unsigned short)pB;
                int cD = cC + 1;
                *(unsigned short*)(vtp + cD * 64 + (slot2 ^ ((cD & 3) << 4))) =
                    (unsigned short)(pB >> 16);
            }
        }

        if ((t & 1) == 0) {
#pragma unroll
            for (int mt = 0; mt < 4; ++mt) paE[mt] = pa[mt];
#pragma unroll
            for (int r = 0; r < 4; ++r) hrE[r] = hr[r];
        } else {
            // E in sigma A-layout: j 0..3 from even iter, 4..7 from odd iter
            bf16x8 eA[4];
#pragma unroll
            for (int mt = 0; mt < 4; ++mt) {
                union { bf16x8 v; unsigned int u[4]; } E;
                E.u[0] = pkbf(fexp2(paE[mt][0]-hrE[0]), fexp2(paE[mt][1]-hrE[1]));
                E.u[1] = pkbf(fexp2(paE[mt][2]-hrE[2]), fexp2(paE[mt][3]-hrE[3]));
                E.u[2] = pkbf(fexp2(pa[mt][0]-hr[0]),   fexp2(pa[mt][1]-hr[1]));
                E.u[3] = pkbf(fexp2(pa[mt][2]-hr[2]),   fexp2(pa[mt][3]-hr[3]));
                eA[mt] = E.v;
            }
            const char* vb2 = (const char*)vT + wid * 8192 + ((t >> 1) & 1) * 4096;
            bf16x8 vB[4];
#pragma unroll
            for (int ct = 0; ct < 4; ++ct) {
                int c = ct * 16 + l15;
                vB[ct] = *(const bf16x8*)(vb2 + c * 64 + ((16 * g) ^ ((c & 3) << 4)));
            }
#pragma unroll
            for (int mt = 0; mt < 4; ++mt) {
#pragma unroll
                for (int ct = 0; ct < 4; ++ct)
                    acc[mt][ct] = MFMA(eA[mt], vB[ct], acc[mt][ct]);
                acc[mt][4] = MFMA(eA[mt], onef, acc[mt][4]);
            }
        }
    };

    float4 kA[4], vA[4], kB[4], vB_[4], kC[4], vC[4];
    loadX(0, kA, vA);
    loadX(1, kB, vB_);
    body(0, kA, vA, kC, vC);
    body(1, kB, vB_, kA, vA);
    body(2, kC, vC, kB, vB_);
    body(3, kA, vA, kC, vC);
    body(4, kB, vB_, kA, vA);
    body(5, kC, vC, kB, vB_);
    body(6, kA, vA, kC, vC);
    body(7, kB, vB_, kA, vA);

    // cross-wave reduce (only barriers in the kernel), then write partial
    for (int i = tid; i < M_ * CPK_; i += 256) red[i] = 0.f;
    __syncthreads();
    for (int w = 0; w < 4; ++w) {
        if (wid == w) {
#pragma unroll
            for (int mt = 0; mt < 4; ++mt)
#pragma unroll
                for (int ct = 0; ct < 5; ++ct)
#pragma unroll
                    for (int r = 0; r < 4; ++r)
                        red[(mt*16 + 4*g + r) * CPK_ + ct*16 + l15] += acc[mt][ct][r];
        }
        __syncthreads();
    }
    float* dst = partial + ((size_t)bh * NCH_ + chunk) * (M_ * CPK_);
    for (int i = tid; i < M_ * CPK_; i += 256) dst[i] = red[i];
}

// ---------------------------------------------------------------------------
// Reduce partials over chunks -> buf1[bh][m][CPK_]
// ---------------------------------------------------------------------------
__global__ void __launch_bounds__(256)
fa_r(const float* __restrict__ partial, float* __restrict__ buf1, int nch)
{
    int e = blockIdx.x * 256 + threadIdx.x;
    if (e >= BH_ * M_ * CPK_) return;
    int bh = e / (M_ * CPK_);
    int r  = e - bh * (M_ * CPK_);
    const float* src = partial + (size_t)bh * nch * (M_ * CPK_) + r;
    float s0 = 0.f, s1 = 0.f, s2 = 0.f, s3 = 0.f;
    int ch = 0;
    for (; ch + 4 <= nch; ch += 4) {
        s0 += src[(size_t)(ch + 0) * (M_ * CPK_)];
        s1 += src[(size_t)(ch + 1) * (M_ * CPK_)];
        s2 += src[(size_t)(ch + 2) * (M_ * CPK_)];
        s3 += src[(size_t)(ch + 3) * (M_ * CPK_)];
    }
    for (; ch < nch; ++ch) s0 += src[(size_t)ch * (M_ * CPK_)];
    buf1[e] = (s0 + s1) + (s2 + s3);
}

// ---------------------------------------------------------------------------
// Phase Q: P = mfma(Qscaled, projT); e = exp2(P - h);
// Out^T-tiles: D[c][qrow] = mfma(buf1T, E_T); den = row c=64; out = num/den.
// ---------------------------------------------------------------------------
__global__ void __launch_bounds__(256)
fa_q(const float* __restrict__ qs, const float* __restrict__ proj,
     const float* __restrict__ buf1, float* __restrict__ out)
{
    const int chunk = blockIdx.x;
    const int bh    = blockIdx.y;
    const int b = bh >> 3, h = bh & 7;
    const int tid = threadIdx.x, wid = tid >> 6, lane = tid & 63;
    const int l15 = lane & 15, g = lane >> 4;

    __shared__ __align__(16) char eLb[2][TILE * M_ * 2];   // [qrow][m] bf16, swz by qrow
    __shared__ __align__(16) char b1tb[CPK_ * M_ * 2];     // [c][m] bf16, swz by c

    const int rows = S_ / NCHQ;
    const int s0 = chunk * rows;
    const size_t rs = (size_t)H_ * D_;
    const float* qb = qs + ((size_t)b * S_ * H_ + h) * D_;

    // stage buf1^T into LDS (c rows 65..79 are zeros in buf1 already)
    const float* b1 = buf1 + (size_t)bh * (M_ * CPK_);
    for (int i = tid; i < M_ * CPK_; i += 256) {
        int m = i / CPK_, c = i - m * CPK_;
        *(unsigned short*)(b1tb + SWZ(c * 128 + 2 * m, c)) = f2bf(b1[i]);
    }

    bf16x8 pf[4][2];
#pragma unroll
    for (int mt = 0; mt < 4; ++mt)
#pragma unroll
        for (int kk = 0; kk < 2; ++kk) {
            const float* p = proj + (mt * 16 + l15) * D_ + kk * 32 + g * 8;
            float4 a = *(const float4*)p, c = *(const float4*)(p + 4);
            union { bf16x8 v; unsigned int u[4]; } F;
            F.u[0] = pkbf(a.x, a.y); F.u[1] = pkbf(a.z, a.w);
            F.u[2] = pkbf(c.x, c.y); F.u[3] = pkbf(c.z, c.w);
            pf[mt][kk] = F.v;
        }
    __syncthreads();

    // buf1^T A-fragments, read once: A[c][m]: c = ci*16+l15, m = g*8+j (+32*kk)
    bf16x8 af3[5][2];
#pragma unroll
    for (int ci = 0; ci < 5; ++ci)
#pragma unroll
        for (int kk = 0; kk < 2; ++kk) {
            int c = ci * 16 + l15;
            af3[ci][kk] = *(const bf16x8*)(b1tb + SWZ(c * 128 + 16 * g + 64 * kk, c));
        }

    auto loadQ = [&](int t, float4* qp) {
        int sb = s0 + t * TILE;
        const float* qrow = qb + (size_t)(sb + wid * 16 + l15) * rs;
        qp[0] = *(const float4*)(qrow + g * 8);
        qp[1] = *(const float4*)(qrow + g * 8 + 4);
        qp[2] = *(const float4*)(qrow + 32 + g * 8);
        qp[3] = *(const float4*)(qrow + 32 + g * 8 + 4);
    };

    auto body = [&](int t, int p, const float4* qc, float4* qn) {
        if (t + 1 < QTILES) loadQ(t + 1, qn);

        float kx[16];
#pragma unroll
        for (int i = 0; i < 4; ++i) {
            kx[4 * i + 0] = qc[i].x * XS_; kx[4 * i + 1] = qc[i].y * XS_;
            kx[4 * i + 2] = qc[i].z * XS_; kx[4 * i + 3] = qc[i].w * XS_;
        }
        float sq = 0.f;
#pragma unroll
        for (int j = 0; j < 16; ++j) sq += kx[j] * kx[j];
        sq += __shfl_xor(sq, 16);
        sq += __shfl_xor(sq, 32);
        float hrow = sq * HS_ + 3.0f;

        union { bf16x8 v; unsigned int u[4]; } A0, A1;
#pragma unroll
        for (int i = 0; i < 4; ++i) {
            A0.u[i] = pkbf(kx[2 * i], kx[2 * i + 1]);
            A1.u[i] = pkbf(kx[8 + 2 * i], kx[9 + 2 * i]);
        }

        f32x4 pa[4];
#pragma unroll
        for (int mt = 0; mt < 4; ++mt) {
            pa[mt] = (f32x4){0.f, 0.f, 0.f, 0.f};
            pa[mt] = MFMA(A0.v, pf[mt][0], pa[mt]);
            pa[mt] = MFMA(A1.v, pf[mt][1], pa[mt]);
        }

        float hr[4];
#pragma unroll
        for (int r = 0; r < 4; ++r) hr[r] = __shfl(hrow, 4 * g + r);

        char* elp = eLb[p];
#pragma unroll
        for (int mt = 0; mt < 4; ++mt) {
            int m = mt * 16 + l15;
            float e0 = fexp2(pa[mt][0] - hr[0]);
            float e1 = fexp2(pa[mt][1] - hr[1]);
            float e2 = fexp2(pa[mt][2] - hr[2]);
            float e3 = fexp2(pa[mt][3] - hr[3]);
            unsigned int p01 = pkbf(e0, e1), p23 = pkbf(e2, e3);
            int q0 = wid * 16 + 4 * g;
            *(unsigned short*)(elp + SWZ((q0 + 0) * 128 + 2 * m, q0 + 0)) =
                (unsigned short)p01;
            *(unsigned short*)(elp + SWZ((q0 + 1) * 128 + 2 * m, q0 + 1)) =
                (unsigned short)(p01 >> 16);
            *(unsigned short*)(elp + SWZ((q0 + 2) * 128 + 2 * m, q0 + 2)) =
                (unsigned short)p23;
            *(unsigned short*)(elp + SWZ((q0 + 3) * 128 + 2 * m, q0 + 3)) =
                (unsigned short)(p23 >> 16);
        }
        __syncthreads();

        bf16x8 b3[2];
        {
            int qrow = wid * 16 + l15;
            b3[0] = *(const bf16x8*)(elp + SWZ(qrow * 128 + 16 * g, qrow));
            b3[1] = *(const bf16x8*)(elp + SWZ(qrow * 128 + 16 * g + 64, qrow));
        }
        f32x4 dt[5];
#pragma unroll
        for (int ci = 0; ci < 5; ++ci) {
            dt[ci] = (f32x4){0.f, 0.f, 0.f, 0.f};
            dt[ci] = MFMA(af3[ci][0], b3[0], dt[ci]);
            dt[ci] = MFMA(af3[ci][1], b3[1], dt[ci]);
        }

        float den = __shfl(dt[4][0], l15);      // lanes g==0 hold den[qrow=l15]
        float rd = 1.0f / fmaxf(den, EPS_);

        int sg = s0 + t * TILE + wid * 16 + l15;
        size_t base = (((size_t)b * S_ + sg) * H_ + h) * D_;
#pragma unroll
        for (int ci = 0; ci < 4; ++ci) {
            f32x4 o;
#pragma unroll
            for (int r = 0; r < 4; ++r) o[r] = dt[ci][r] * rd;
            *(f32x4*)(out + base + ci * 16 + 4 * g) = o;
        }
    };

    float4 qa[4], qb2[4];
    loadQ(0, qa);
    for (int t = 0; t < QTILES; t += 2) {
        body(t, 0, qa, qb2);
        body(t + 1, 1, qb2, qa);
    }
}

extern "C" void kernel_launch(void* const* d_in, const int* in_sizes, int n_in,
                              void* d_out, int out_size, void* d_ws, size_t ws_size,
                              hipStream_t stream)
{
    const float* qs   = (const float*)d_in[0];
    const float* ks   = (const float*)d_in[1];
    const float* vs   = (const float*)d_in[2];
    const float* proj = (const float*)d_in[3];
    float* out = (float*)d_out;

    float* partial = (float*)d_ws;                // BH*NCH_*M*CPK
    float* buf1 = partial + (size_t)BH_ * NCH_ * (M_ * CPK_);

    fa_k<<<dim3(NCH_, BH_), 256, 0, stream>>>(ks, vs, proj, partial);
    int nred = (BH_ * M_ * CPK_ + 255) / 256;
    fa_r<<<dim3(nred), 256, 0, stream>>>(partial, buf1, NCH_);
    fa_q<<<dim3(NCHQ, BH_), 256, 0, stream>>>(qs, proj, buf1, out);
}